// Round 1
// baseline (319.489 us; speedup 1.0000x reference)
//
#include <hip/hip_runtime.h>
#include <stdint.h>

// Problem constants
#define CIN   256
#define COUT  256
#define HH    56
#define WW    56
#define BB    32
#define HP    58            // padded H
#define WP    58            // padded W
#define KTOT  2304          // CIN*3*3, K order = (kh, kw, ci), ci fastest
#define NPIX  (BB*HH*WW)    // 100352
#define OHW   (HH*WW)       // 3136

// Workspace layout
#define WS_AMAX_OFF   0
#define WS_WPACK_OFF  256
#define WPACK_BYTES   (COUT*KTOT)       // 589824
#define WS_XPAD_OFF   (1<<20)
#define XPAD_BYTES    (BB*HP*WP*CIN)    // 27557888

typedef __attribute__((ext_vector_type(4))) int i32x4;

// ---------------------------------------------------------------- absmax ----
__global__ void absmax_kernel(const float* __restrict__ x,
                              unsigned int* __restrict__ amax, int n4) {
  int tid = blockIdx.x * blockDim.x + threadIdx.x;
  int stride = gridDim.x * blockDim.x;
  const float4* x4 = (const float4*)x;
  float m = 0.0f;
  for (int i = tid; i < n4; i += stride) {
    float4 v = x4[i];
    m = fmaxf(m, fmaxf(fmaxf(fabsf(v.x), fabsf(v.y)),
                       fmaxf(fabsf(v.z), fabsf(v.w))));
  }
#pragma unroll
  for (int off = 32; off >= 1; off >>= 1)
    m = fmaxf(m, __shfl_xor(m, off, 64));
  __shared__ float red[4];
  int lane = threadIdx.x & 63, wv = threadIdx.x >> 6;
  if (lane == 0) red[wv] = m;
  __syncthreads();
  if (threadIdx.x == 0) {
    float mm = fmaxf(fmaxf(red[0], red[1]), fmaxf(red[2], red[3]));
    atomicMax(amax, __float_as_uint(mm));  // all values >= 0: uint order == float order
  }
}

// -------------------------------------------------- quantize + pad + NHWC ----
// x: NCHW fp32 -> xpad: [B][HP][WP][CIN] int8 (halo pre-zeroed by memset).
// One block: (ci_block of 64) x (one image row h) for one b. LDS transpose.
__global__ void quant_kernel(const float* __restrict__ x,
                             const unsigned int* __restrict__ amax,
                             int8_t* __restrict__ xpad) {
  const int cb = blockIdx.x;   // 0..3
  const int h  = blockIdx.y;   // 0..55
  const int b  = blockIdx.z;   // 0..31
  const int ci0 = cb * 64;
  const float xs = __uint_as_float(*amax) / 127.0f;  // matches reference x_scale
  __shared__ __align__(16) int8_t t[56 * 68];        // [w][ci_local], stride 68 (17 banks)
  const int tid = threadIdx.x;
  for (int e = tid; e < 64 * 56; e += 256) {
    int ci = e / 56;
    int w  = e - ci * 56;
    float v = x[(((b * CIN) + ci0 + ci) * HH + h) * WW + w];
    float q = rintf(v / xs);                         // IEEE div + round-half-even (== jnp)
    q = fminf(127.0f, fmaxf(-127.0f, q));
    t[w * 68 + ci] = (int8_t)(int)q;
  }
  __syncthreads();
  uint8_t* dst = (uint8_t*)xpad;
  for (int e = tid; e < 56 * 16; e += 256) {
    int w = e >> 4, c4 = e & 15;
    unsigned int v = *(const unsigned int*)&t[w * 68 + c4 * 4];
    *(unsigned int*)(dst + ((((b * HP) + h + 1) * WP + (w + 1)) << 8) + ci0 + c4 * 4) = v;
  }
}

// ------------------------------------------------------------ weight pack ----
// wq: [cout][ci][kh][kw] int32 -> wp: [cout][kh][kw][ci] int8
__global__ void wpack_kernel(const int* __restrict__ wq, int8_t* __restrict__ wp) {
  int i = blockIdx.x * 256 + threadIdx.x;   // grid covers 589824 exactly
  int ci   = i & 255;
  int t    = i >> 8;
  int khkw = t % 9;
  int co   = t / 9;
  wp[i] = (int8_t)wq[(co * CIN + ci) * 9 + khkw];
}

// ------------------------------------------------------------------- conv ----
// Implicit GEMM: A = wp [256 x 2304], B^T = im2col(xpad) [100352 x 2304].
// 128x128 tile, BK=64 (one (kh,kw) ci-quarter per step), 36 K-steps.
// 4 waves (2x2), each wave 4x4 frags of mfma_i32_16x16x64_i8 (64x64 out/wave).
__global__ __launch_bounds__(256, 2)
void conv_kernel(const int8_t* __restrict__ xpad, const int8_t* __restrict__ wp,
                 const unsigned int* __restrict__ amax,
                 const float* __restrict__ wscale,
                 const float* __restrict__ bias, float* __restrict__ out) {
  __shared__ __align__(16) int8_t As[2][128 * 64];
  __shared__ __align__(16) int8_t Bs[2][128 * 64];

  const int tid  = threadIdx.x;
  const int lane = tid & 63;
  const int wv   = tid >> 6;       // wave 0..3
  const int wm   = wv >> 1;        // wave row (cout)
  const int wn   = wv & 1;         // wave col (pixel)

  // bijective XCD swizzle (grid 1568 % 8 == 0)
  int bx = blockIdx.x;
  const int cpx = gridDim.x >> 3;
  bx = (bx & 7) * cpx + (bx >> 3);
  const int m0 = (bx & 1) << 7;    // cout tile base
  const int n0 = (bx >> 1) << 7;   // pixel tile base

  // Staging sources. Tile rows are 64B = 4 x 16B segs; linear LDS fill task
  // s = issue*256 + tid -> (row r = s>>2, phys seg = s&3). Source uses the
  // INVERSE swizzle slog = phys ^ ((r>>1)&3) so swizzled reads see logical data.
  const int8_t* gA[2];
  const int8_t* gB[2];
#pragma unroll
  for (int i = 0; i < 2; ++i) {
    int s = i * 256 + tid;
    int r = s >> 2;
    int slog = (s & 3) ^ ((r >> 1) & 3);
    gA[i] = wp + (m0 + r) * KTOT + slog * 16;
    int p  = n0 + r;
    int ow = p % 56;
    int t1 = p / 56;
    int oh = t1 % 56;
    int b  = t1 / 56;
    gB[i] = xpad + (((b * HP + oh) * WP) + ow) * 256 + slog * 16;  // +kh,+kw,+ci0 uniform per step
  }

  const int rr = lane & 15;
  const int physseg = ((lane >> 4) ^ ((rr >> 1) & 3)) << 4;  // swizzled 16B seg for ds_read

  auto stage = [&](int bsel, int kk) {
    int khkw = kk >> 2;
    int kh = khkw / 3;
    int kw = khkw - kh * 3;
    int koffB = ((kh * WP + kw) << 8) + ((kk & 3) << 6);
    int koffA = kk << 6;
#pragma unroll
    for (int i = 0; i < 2; ++i) {
      __builtin_amdgcn_global_load_lds(
          (const __attribute__((address_space(1))) void*)(gA[i] + koffA),
          (__attribute__((address_space(3))) void*)&As[bsel][i * 4096 + wv * 1024],
          16, 0, 0);
      __builtin_amdgcn_global_load_lds(
          (const __attribute__((address_space(1))) void*)(gB[i] + koffB),
          (__attribute__((address_space(3))) void*)&Bs[bsel][i * 4096 + wv * 1024],
          16, 0, 0);
    }
  };

  i32x4 acc[4][4] = {};

  stage(0, 0);
  __syncthreads();
  int buf = 0;
  for (int kk = 0; kk < 36; ++kk) {
    if (kk < 35) stage(buf ^ 1, kk + 1);
    const int8_t* Ab = As[buf];
    const int8_t* Bb = Bs[buf];
    i32x4 a[4], b[4];
#pragma unroll
    for (int mi = 0; mi < 4; ++mi)
      a[mi] = *(const i32x4*)(Ab + (((wm << 6) + (mi << 4) + rr) << 6) + physseg);
#pragma unroll
    for (int ni = 0; ni < 4; ++ni)
      b[ni] = *(const i32x4*)(Bb + (((wn << 6) + (ni << 4) + rr) << 6) + physseg);
#pragma unroll
    for (int mi = 0; mi < 4; ++mi)
#pragma unroll
      for (int ni = 0; ni < 4; ++ni)
        acc[mi][ni] = __builtin_amdgcn_mfma_i32_16x16x64_i8(a[mi], b[ni], acc[mi][ni], 0, 0, 0);
    __syncthreads();
    buf ^= 1;
  }

  // Epilogue: C/D map (dtype-independent): row(cout) = (lane>>4)*4 + reg, col(pix) = lane&15
  const float xs = __uint_as_float(*amax) / 127.0f;
  const float cmul = xs * wscale[0];
#pragma unroll
  for (int ni = 0; ni < 4; ++ni) {
    int p  = n0 + (wn << 6) + (ni << 4) + rr;
    int ow = p % 56;
    int t1 = p / 56;
    int oh = t1 % 56;
    int b  = t1 / 56;
    int obase = b * (COUT * OHW) + oh * 56 + ow;
#pragma unroll
    for (int mi = 0; mi < 4; ++mi) {
      int co = m0 + (wm << 6) + (mi << 4) + ((lane >> 4) << 2);
#pragma unroll
      for (int j = 0; j < 4; ++j) {
        out[obase + (co + j) * OHW] = (float)acc[mi][ni][j] * cmul + bias[co + j];
      }
    }
  }
}

// ------------------------------------------------------------------ launch ----
extern "C" void kernel_launch(void* const* d_in, const int* in_sizes, int n_in,
                              void* d_out, int out_size, void* d_ws, size_t ws_size,
                              hipStream_t stream) {
  const float* x       = (const float*)d_in[0];
  const int*   wq      = (const int*)d_in[1];
  const float* wscale  = (const float*)d_in[2];
  const float* bias    = (const float*)d_in[3];
  float* out = (float*)d_out;

  uint8_t* ws = (uint8_t*)d_ws;
  unsigned int* amax = (unsigned int*)(ws + WS_AMAX_OFF);
  int8_t* wp   = (int8_t*)(ws + WS_WPACK_OFF);
  int8_t* xpad = (int8_t*)(ws + WS_XPAD_OFF);

  hipMemsetAsync(amax, 0, 4, stream);
  hipMemsetAsync(xpad, 0, XPAD_BYTES, stream);  // zeroes the halo (and interior, overwritten)

  absmax_kernel<<<2048, 256, 0, stream>>>(x, amax, (NPIX * CIN) / 4);
  quant_kernel<<<dim3(4, 56, 32), 256, 0, stream>>>(x, amax, xpad);
  wpack_kernel<<<WPACK_BYTES / 256, 256, 0, stream>>>(wq, wp);
  conv_kernel<<<(NPIX / 128) * (COUT / 128), 256, 0, stream>>>(xpad, wp, amax, wscale, bias, out);
}